// Round 5
// baseline (427.314 us; speedup 1.0000x reference)
//
#include <hip/hip_runtime.h>

// CRF forward: B=512, T=1024, N=64. One 64-lane wave per batch.
// Round 5 change vs round 4:
//  - E is staged through LDS. Rounds 3/4 proved (VGPR_Count=44 under both
//    launch_bounds) that the allocator REMATERIALIZES E inside the loop:
//    each E value's def chain (invariant global load -> mul -> v_exp) is
//    trivially rematerializable, so instead of keeping 64 floats live it
//    re-derives them every step (~650 cy/step of hidden latency).
//    An LDS read is NOT rematerializable -> E finally stays in VGPRs.
//  - LDS layout: ET[j][i] = exp(trans[i][j]), stride 68 floats (272 B,
//    16B-aligned for b128, breaks the 64-stride all-lanes-same-bank case).
//    Staging + readback are one-time, outside the T-loop.

constexpr int Tt = 1024;
constexpr int Nn = 64;
constexpr int STRIDE = 68;  // 64 + 4 pad; 68*4 = 272 B, 16B-aligned

// broadcast p from lane L (all 64 lanes always active)
#define RL(L) __uint_as_float((unsigned)__builtin_amdgcn_readlane((int)__float_as_uint(p), (L)))

#define FMA4(K, EV)                               \
    a0 = __builtin_fmaf(RL(4*(K)+0), (EV).x, a0); \
    a1 = __builtin_fmaf(RL(4*(K)+1), (EV).y, a1); \
    a2 = __builtin_fmaf(RL(4*(K)+2), (EV).z, a2); \
    a3 = __builtin_fmaf(RL(4*(K)+3), (EV).w, a3);

__global__ __launch_bounds__(64, 1) void crf_fwd(
    const float* __restrict__ unary,
    const int*   __restrict__ lengths,
    const float* __restrict__ trans,
    float*       __restrict__ out)
{
    const int b = blockIdx.x;
    const int j = threadIdx.x;

    __shared__ float ET[Nn * STRIDE];

    // Stage E^T into LDS: lane j handles column j of trans (coalesced global
    // reads), writes row j of ET. One-time cost.
    #pragma unroll
    for (int i = 0; i < Nn; ++i)
        ET[j * STRIDE + i] = __expf(trans[i * Nn + j]);
    __syncthreads();

    // Read column j of E (= row j of ET) into 16 named float4 registers.
    const float4* etj = (const float4*)&ET[j * STRIDE];
    float4 e0  = etj[0],  e1  = etj[1],  e2  = etj[2],  e3  = etj[3];
    float4 e4  = etj[4],  e5  = etj[5],  e6  = etj[6],  e7  = etj[7];
    float4 e8  = etj[8],  e9  = etj[9],  e10 = etj[10], e11 = etj[11];
    float4 e12 = etj[12], e13 = etj[13], e14 = etj[14], e15 = etj[15];

    int len = lengths[b];
    len = len < 1 ? 1 : (len > Tt ? Tt : len);

    const float* ub = unary + (size_t)b * Tt * Nn;
    float alpha = ub[j];  // t = 0

    // Prefetch u for steps 1..4 (clamped indices stay inside this batch row).
    float u_cur[4];
    #pragma unroll
    for (int k = 0; k < 4; ++k) {
        int t = 1 + k;
        u_cur[k] = ub[(t < Tt ? t : Tt - 1) * Nn + j];
    }

    for (int t0 = 1; t0 < len; t0 += 4) {
        // Next chunk's loads stay in flight (no barrier in the loop).
        float u_nxt[4];
        #pragma unroll
        for (int k = 0; k < 4; ++k) {
            int t = t0 + 4 + k;
            u_nxt[k] = ub[(t < Tt ? t : Tt - 1) * Nn + j];
        }

        #pragma unroll
        for (int k = 0; k < 4; ++k) {
            if (t0 + k >= len) break;  // wave-uniform

            // Wave-uniform offset (recurrence is offset-invariant; lane
            // spread of alpha bounded ~12, exp(12) safe in fp32).
            float sf = __uint_as_float(
                (unsigned)__builtin_amdgcn_readfirstlane((int)__float_as_uint(alpha)));
            float p = __expf(alpha - sf);

            float a0 = 0.f, a1 = 0.f, a2 = 0.f, a3 = 0.f;
            FMA4(0,  e0);  FMA4(1,  e1);  FMA4(2,  e2);  FMA4(3,  e3);
            FMA4(4,  e4);  FMA4(5,  e5);  FMA4(6,  e6);  FMA4(7,  e7);
            FMA4(8,  e8);  FMA4(9,  e9);  FMA4(10, e10); FMA4(11, e11);
            FMA4(12, e12); FMA4(13, e13); FMA4(14, e14); FMA4(15, e15);
            float z = (a0 + a1) + (a2 + a3);

            alpha = sf + u_cur[k] + __logf(z);
        }

        #pragma unroll
        for (int k = 0; k < 4; ++k) u_cur[k] = u_nxt[k];
    }

    // out[b] = logsumexp_j(alpha_j) — exact max (one-time cost).
    float m = alpha;
    #pragma unroll
    for (int k = 32; k >= 1; k >>= 1)
        m = fmaxf(m, __shfl_xor(m, k, 64));
    float e = __expf(alpha - m);
    float ssum = e;
    #pragma unroll
    for (int k = 32; k >= 1; k >>= 1)
        ssum += __shfl_xor(ssum, k, 64);
    if (j == 0) out[b] = m + __logf(ssum);
}

extern "C" void kernel_launch(void* const* d_in, const int* in_sizes, int n_in,
                              void* d_out, int out_size, void* d_ws, size_t ws_size,
                              hipStream_t stream) {
    const float* unary   = (const float*)d_in[0];
    const int*   lengths = (const int*)d_in[1];
    const float* trans   = (const float*)d_in[2];
    float*       out     = (float*)d_out;

    const int Bb = in_sizes[1];  // 512
    crf_fwd<<<Bb, 64, 0, stream>>>(unary, lengths, trans, out);
}

// Round 6
// 384.594 us; speedup vs baseline: 1.1111x; 1.1111x over previous
//
#include <hip/hip_runtime.h>

// CRF forward: B=512, T=1024, N=64.
// Round 6 changes vs round 5:
//  1) readlane broadcast removed. R4 (E remat from global) and R5 (E from
//     LDS) timed IDENTICALLY -> E sourcing was never the critical path; the
//     64 dependent v_readlane->v_fma pairs were (~663 cy/step incl. SGPR
//     hazard waits). Replaced by barrier-free intra-wave LDS broadcast:
//     ds_write p, then 16 uniform ds_read_b128 (wave is lock-step; only
//     lgkmcnt ordering needed, no s_barrier, no vmcnt drain).
//  2) fwd/bwd split: out = LSE_i(alpha_m[i] + beta_m[i]) at m=(L-1)/2,
//     beta the backward vector recurrence (beta_{L-1}=0). Two waves per
//     batch (block=128): critical path 1024 -> max 512 steps, and 1024
//     waves fill all 1024 SIMDs.

constexpr int Tt = 1024;
constexpr int Nn = 64;
constexpr int ES = 68;  // E row stride in LDS: 64+4 pad, 272 B (16B-aligned)

#define FMA4(K, EV) { float4 pv = p4[K];                \
    a0 = __builtin_fmaf(pv.x, (EV).x, a0);              \
    a1 = __builtin_fmaf(pv.y, (EV).y, a1);              \
    a2 = __builtin_fmaf(pv.z, (EV).z, a2);              \
    a3 = __builtin_fmaf(pv.w, (EV).w, a3); }

__global__ __launch_bounds__(128, 1) void crf_fwd(
    const float* __restrict__ unary,
    const int*   __restrict__ lengths,
    const float* __restrict__ trans,
    float*       __restrict__ out)
{
    const int b    = blockIdx.x;
    const int tid  = threadIdx.x;
    const int w    = tid >> 6;   // 0 = forward wave, 1 = backward wave
    const int lane = tid & 63;

    __shared__ float Ecol[Nn * ES];   // Ecol[j*ES+i] = exp(trans[i][j])
    __shared__ float Erow[Nn * ES];   // Erow[i*ES+j] = exp(trans[i][j])
    __shared__ float shp[2][Nn];      // per-wave p broadcast slot
    __shared__ float shb[Nn];         // beta at the midpoint (combine)

    // One-time staging of E = exp(trans), both orientations. Coalesced reads.
    #pragma unroll
    for (int c = 0; c < (Nn * Nn) / 128; ++c) {
        int idx = c * 128 + tid;
        int i = idx >> 6, j = idx & 63;
        float e = __expf(trans[idx]);
        Erow[i * ES + j] = e;
        Ecol[j * ES + i] = e;
    }
    __syncthreads();

    // Each lane's 64 E values (fwd: column `lane`; bwd: row `lane`) into
    // named float4 registers.
    const float4* eb = (const float4*)((w == 0) ? &Ecol[lane * ES]
                                                : &Erow[lane * ES]);
    float4 e0  = eb[0],  e1  = eb[1],  e2  = eb[2],  e3  = eb[3];
    float4 e4  = eb[4],  e5  = eb[5],  e6  = eb[6],  e7  = eb[7];
    float4 e8  = eb[8],  e9  = eb[9],  e10 = eb[10], e11 = eb[11];
    float4 e12 = eb[12], e13 = eb[13], e14 = eb[14], e15 = eb[15];

    int L = lengths[b];
    L = L < 1 ? 1 : (L > Tt ? Tt : L);
    const int m = (L - 1) >> 1;

    const float* ub = unary + (size_t)b * Tt * Nn;

    // Unified loop setup: step s -> time index t = tbase + dir*s.
    const int trips = (w == 0) ? m : (L - 1 - m);
    const int tbase = (w == 0) ? 1 : (L - 1);
    const int dir   = (w == 0) ? 1 : -1;

    float acc = (w == 0) ? ub[lane] : 0.0f;   // alpha_0 or beta_{L-1}
    float* myp = shp[w];
    const float4* p4 = (const float4*)myp;

    // 4-deep u prefetch (clamped step index always maps into [0, L-1]).
    float u_cur[4];
    {
        int smax = trips > 0 ? trips - 1 : 0;
        #pragma unroll
        for (int k = 0; k < 4; ++k) {
            int sc = k < smax ? k : smax;
            u_cur[k] = ub[(tbase + dir * sc) * Nn + lane];
        }
    }

    for (int s0 = 0; s0 < trips; s0 += 4) {
        float u_nxt[4];
        #pragma unroll
        for (int k = 0; k < 4; ++k) {
            int sc = s0 + 4 + k;
            if (sc > trips - 1) sc = trips - 1;
            u_nxt[k] = ub[(tbase + dir * sc) * Nn + lane];
        }

        #pragma unroll
        for (int k = 0; k < 4; ++k) {
            if (s0 + k >= trips) break;  // wave-uniform

            // fwd: p = exp(alpha - s), update = s + u + log z
            // bwd: q = exp(beta + u - s), update = s + log z
            float ui = (w != 0) ? u_cur[k] : 0.0f;
            float uo = (w == 0) ? u_cur[k] : 0.0f;

            float tmp = acc + ui;
            float sf = __uint_as_float(
                (unsigned)__builtin_amdgcn_readfirstlane((int)__float_as_uint(tmp)));
            float p = __expf(tmp - sf);

            myp[lane] = p;  // intra-wave: lgkmcnt ordering only, no barrier

            float a0 = 0.f, a1 = 0.f, a2 = 0.f, a3 = 0.f;
            FMA4(0,  e0);  FMA4(1,  e1);  FMA4(2,  e2);  FMA4(3,  e3);
            FMA4(4,  e4);  FMA4(5,  e5);  FMA4(6,  e6);  FMA4(7,  e7);
            FMA4(8,  e8);  FMA4(9,  e9);  FMA4(10, e10); FMA4(11, e11);
            FMA4(12, e12); FMA4(13, e13); FMA4(14, e14); FMA4(15, e15);
            float z = (a0 + a1) + (a2 + a3);

            acc = sf + uo + __logf(z);
        }

        #pragma unroll
        for (int k = 0; k < 4; ++k) u_cur[k] = u_nxt[k];
    }

    // Combine: out[b] = LSE_i(alpha_m[i] + beta_m[i]).
    if (w == 1) shb[lane] = acc;
    __syncthreads();
    if (w == 0) {
        float v = acc + shb[lane];
        float mx = v;
        #pragma unroll
        for (int k = 32; k >= 1; k >>= 1)
            mx = fmaxf(mx, __shfl_xor(mx, k, 64));
        float ssum = __expf(v - mx);
        #pragma unroll
        for (int k = 32; k >= 1; k >>= 1)
            ssum += __shfl_xor(ssum, k, 64);
        if (lane == 0) out[b] = mx + __logf(ssum);
    }
}

extern "C" void kernel_launch(void* const* d_in, const int* in_sizes, int n_in,
                              void* d_out, int out_size, void* d_ws, size_t ws_size,
                              hipStream_t stream) {
    const float* unary   = (const float*)d_in[0];
    const int*   lengths = (const int*)d_in[1];
    const float* trans   = (const float*)d_in[2];
    float*       out     = (float*)d_out;

    const int Bb = in_sizes[1];  // 512
    crf_fwd<<<Bb, 128, 0, stream>>>(unary, lengths, trans, out);
}

// Round 7
// 324.822 us; speedup vs baseline: 1.3155x; 1.1840x over previous
//
#include <hip/hip_runtime.h>

// CRF forward: B=512, T=1024, N=64. fwd/bwd split, one wave per chain.
// Round 7 changes vs round 6:
//  - R6's 1130 cy/step diagnosed as register-pressure-limited scheduling:
//    VGPR_Count=88 left no room for the 16 in-flight p-reads, so the
//    scheduler serialized them into read->wait->FMA groups, paying the
//    ~120cy LDS latency ~8x per step. Fix: 16 NAMED f4 loads issued
//    before any use (latency paid once), VGPR pressure allowed to rise.
//  - Packed math: f4 ext-vector accumulate -> v_pk_fma_f32 (32 instrs
//    for 64 MACs, halves FMA issue).

typedef float f4 __attribute__((ext_vector_type(4)));

constexpr int Tt = 1024;
constexpr int Nn = 64;
constexpr int ES = 68;  // f32 row stride: 272 B, 16B-aligned, non-pow2

__global__ __launch_bounds__(128, 1) void crf_fwd(
    const float* __restrict__ unary,
    const int*   __restrict__ lengths,
    const float* __restrict__ trans,
    float*       __restrict__ out)
{
    const int b    = blockIdx.x;
    const int tid  = threadIdx.x;
    const int w    = tid >> 6;   // 0 = forward wave, 1 = backward wave
    const int lane = tid & 63;

    __shared__ float Ecol[Nn * ES];   // Ecol[j*ES+i] = exp(trans[i][j])
    __shared__ float Erow[Nn * ES];   // Erow[i*ES+j] = exp(trans[i][j])
    __shared__ f4    shp4[2][Nn / 4]; // per-wave p broadcast (16B-aligned)
    __shared__ float shb[Nn];         // beta at midpoint (combine)

    // One-time staging of E = exp(trans), both orientations.
    #pragma unroll
    for (int c = 0; c < (Nn * Nn) / 128; ++c) {
        int idx = c * 128 + tid;
        int i = idx >> 6, j = idx & 63;
        float e = __expf(trans[idx]);
        Erow[i * ES + j] = e;
        Ecol[j * ES + i] = e;
    }
    __syncthreads();

    // Lane's 64 E values (fwd: column `lane`; bwd: row `lane`) into 16 named f4.
    const f4* eb = (const f4*)((w == 0) ? &Ecol[lane * ES] : &Erow[lane * ES]);
    f4 E0  = eb[0],  E1  = eb[1],  E2  = eb[2],  E3  = eb[3];
    f4 E4  = eb[4],  E5  = eb[5],  E6  = eb[6],  E7  = eb[7];
    f4 E8  = eb[8],  E9  = eb[9],  E10 = eb[10], E11 = eb[11];
    f4 E12 = eb[12], E13 = eb[13], E14 = eb[14], E15 = eb[15];

    int L = lengths[b];
    L = L < 1 ? 1 : (L > Tt ? Tt : L);
    const int m = (L - 1) >> 1;

    const float* ub = unary + (size_t)b * Tt * Nn;

    const int trips = (w == 0) ? m : (L - 1 - m);
    const int tbase = (w == 0) ? 1 : (L - 1);
    const int dir   = (w == 0) ? 1 : -1;

    float acc = (w == 0) ? ub[lane] : 0.0f;   // alpha_0 or beta_{L-1}
    float* myp = (float*)shp4[w];
    const f4* pp = shp4[w];

    // 4-deep u prefetch (clamped indices stay in valid rows).
    float u_cur[4];
    {
        int smax = trips > 0 ? trips - 1 : 0;
        #pragma unroll
        for (int k = 0; k < 4; ++k) {
            int sc = k < smax ? k : smax;
            u_cur[k] = ub[(tbase + dir * sc) * Nn + lane];
        }
    }

    for (int s0 = 0; s0 < trips; s0 += 4) {
        float u_nxt[4];
        #pragma unroll
        for (int k = 0; k < 4; ++k) {
            int sc = s0 + 4 + k;
            if (sc > trips - 1) sc = trips - 1;
            u_nxt[k] = ub[(tbase + dir * sc) * Nn + lane];
        }

        #pragma unroll
        for (int k = 0; k < 4; ++k) {
            if (s0 + k >= trips) break;  // wave-uniform

            // fwd: p = exp(alpha - s), update = s + u + log z
            // bwd: q = exp(beta + u - s), update = s + log z
            float ui = (w != 0) ? u_cur[k] : 0.0f;
            float uo = (w == 0) ? u_cur[k] : 0.0f;

            float tmpv = acc + ui;
            float sf = __uint_as_float(
                (unsigned)__builtin_amdgcn_readfirstlane((int)__float_as_uint(tmpv)));
            float p = __expf(tmpv - sf);

            myp[lane] = p;  // intra-wave ds_write; same-wave DS ops are in-order

            // All 16 reads named and issued before any use: one latency hit.
            f4 q0  = pp[0],  q1  = pp[1],  q2  = pp[2],  q3  = pp[3];
            f4 q4  = pp[4],  q5  = pp[5],  q6  = pp[6],  q7  = pp[7];
            f4 q8  = pp[8],  q9  = pp[9],  q10 = pp[10], q11 = pp[11];
            f4 q12 = pp[12], q13 = pp[13], q14 = pp[14], q15 = pp[15];

            f4 A0 = {0.f, 0.f, 0.f, 0.f};
            f4 A1 = {0.f, 0.f, 0.f, 0.f};
            f4 A2 = {0.f, 0.f, 0.f, 0.f};
            f4 A3 = {0.f, 0.f, 0.f, 0.f};
            A0 = q0  * E0  + A0;  A1 = q1  * E1  + A1;
            A2 = q2  * E2  + A2;  A3 = q3  * E3  + A3;
            A0 = q4  * E4  + A0;  A1 = q5  * E5  + A1;
            A2 = q6  * E6  + A2;  A3 = q7  * E7  + A3;
            A0 = q8  * E8  + A0;  A1 = q9  * E9  + A1;
            A2 = q10 * E10 + A2;  A3 = q11 * E11 + A3;
            A0 = q12 * E12 + A0;  A1 = q13 * E13 + A1;
            A2 = q14 * E14 + A2;  A3 = q15 * E15 + A3;
            f4 S = (A0 + A1) + (A2 + A3);
            float z = (S.x + S.y) + (S.z + S.w);

            acc = sf + uo + __logf(z);
        }

        #pragma unroll
        for (int k = 0; k < 4; ++k) u_cur[k] = u_nxt[k];
    }

    // Combine: out[b] = LSE_i(alpha_m[i] + beta_m[i]).
    if (w == 1) shb[lane] = acc;
    __syncthreads();
    if (w == 0) {
        float v = acc + shb[lane];
        float mx = v;
        #pragma unroll
        for (int k = 32; k >= 1; k >>= 1)
            mx = fmaxf(mx, __shfl_xor(mx, k, 64));
        float ssum = __expf(v - mx);
        #pragma unroll
        for (int k = 32; k >= 1; k >>= 1)
            ssum += __shfl_xor(ssum, k, 64);
        if (lane == 0) out[b] = mx + __logf(ssum);
    }
}

extern "C" void kernel_launch(void* const* d_in, const int* in_sizes, int n_in,
                              void* d_out, int out_size, void* d_ws, size_t ws_size,
                              hipStream_t stream) {
    const float* unary   = (const float*)d_in[0];
    const int*   lengths = (const int*)d_in[1];
    const float* trans   = (const float*)d_in[2];
    float*       out     = (float*)d_out;

    const int Bb = in_sizes[1];  // 512
    crf_fwd<<<Bb, 128, 0, stream>>>(unary, lengths, trans, out);
}